// Round 5
// baseline (490.930 us; speedup 1.0000x reference)
//
#include <hip/hip_runtime.h>
#include <math.h>

#define D 128
#define LLEN 200
#define SLEN 50
#define CH 64
#define ESTR 132          // floats; 528B row stride = 33*16 -> 16B-aligned rows, bank-balanced
#define NEG (-1e9f)

__device__ __forceinline__ float wave_red_sum(float v) {
#pragma unroll
  for (int m = 32; m >= 1; m >>= 1) v += __shfl_xor(v, m, 64);
  return v;
}
// 256-thread block sum; ALL threads must call.
__device__ __forceinline__ float block_sum(float v, float* red) {
  v = wave_red_sum(v);
  if ((threadIdx.x & 63) == 0) red[threadIdx.x >> 6] = v;
  __syncthreads();
  v = red[0] + red[1] + red[2] + red[3];
  __syncthreads();
  return v;
}

__global__ void __launch_bounds__(256, 4) din_kernel(
    const float* __restrict__ user_table, const float* __restrict__ item_table,
    const float* __restrict__ W1, const float* __restrict__ b1,
    const float* __restrict__ W2, const float* __restrict__ b2,
    const int* __restrict__ user_inputs, const int* __restrict__ L_inputs,
    const int* __restrict__ S_inputs, const int* __restrict__ item_inputs,
    float* __restrict__ out) {
  __shared__ __align__(16) float ebuf[CH * ESTR];  // 33,792B rows + aliased scratch
  __shared__ float hspart[4 * 65];
  __shared__ float w_sh[CH];
  __shared__ int rows1[LLEN];
  __shared__ int rowsS[SLEN];
  __shared__ float upart_sh[16];
  __shared__ float red_sh[4];

  const int b = blockIdx.x;
  const int tid = threadIdx.x;
  const int lane = tid & 63;
  const int w = __builtin_amdgcn_readfirstlane(tid >> 6);  // wave id (W1 s_load)
  const int q = tid & 31, g = tid >> 5;                    // float4-accumulate roles
  const float4* it4 = reinterpret_cast<const float4*>(item_table);

  // ---- prolog: indices + user embedding (aliased into ebuf) ----
  float* u_sh = &ebuf[0];
  float* part = &ebuf[128];
  if (tid < D) u_sh[tid] = user_table[(size_t)user_inputs[b] * D + tid];
  if (tid < LLEN) rows1[tid] = L_inputs[(size_t)b * LLEN + tid];
  if (tid < SLEN) rowsS[tid] = S_inputs[(size_t)b * SLEN + tid];
  __syncthreads();

  // ---- issue chunk-0 prefetch (overlaps upart compute) ----
  float4 v[8];
#pragma unroll
  for (int it = 0; it < 8; ++it) {
    int s = tid + it * 256;  // < 2048 always for chunk 0
    int gid = rows1[s >> 5];
    if (gid < 0) gid = 0;
    v[it] = it4[(size_t)gid * 32 + (s & 31)];
  }

  // ---- u_part[j] = b1[j] + u @ W1[0:128,:] ----
  {
    int j = tid & 15, gg = tid >> 4;
    float p = 0.f;
#pragma unroll
    for (int t = 0; t < 8; ++t) {
      int d = gg * 8 + t;
      p = fmaf(u_sh[d], W1[d * 16 + j], p);
    }
    part[tid] = p;
  }
  __syncthreads();
  if (tid < 16) {
    float s = b1[tid];
#pragma unroll
    for (int gg = 0; gg < 16; ++gg) s += part[gg * 16 + tid];
    upart_sh[tid] = s;
  }
  __syncthreads();

  const float b2v = b2[0];
  const float w2a = W2[4 * w + 0], w2b = W2[4 * w + 1];
  const float w2c = W2[4 * w + 2], w2d = W2[4 * w + 3];

  float pacc = 0.f;
  float4 uacc = make_float4(0.f, 0.f, 0.f, 0.f);

  // ================= stage 1: 4 chunks {64,64,64,8} =================
  for (int c = 0; c < 4; ++c) {
    const int base = c * CH;
    const int cnt = (base + CH <= LLEN) ? CH : (LLEN - base);
    const int nslot = cnt * 32;

    // -- write prefetched rows to LDS (aligned ds_write_b128, balanced) --
#pragma unroll
    for (int it = 0; it < 8; ++it) {
      int s = tid + it * 256;
      if (s < nslot)
        *reinterpret_cast<float4*>(&ebuf[(s >> 5) * ESTR + 4 * (s & 31)]) = v[it];
    }
    __syncthreads();

    // -- issue next prefetch: chunk c+1, or stage-2 rows on last chunk --
    if (c < 3) {
      const int nbase = (c + 1) * CH;
      const int nn = ((nbase + CH <= LLEN) ? CH : (LLEN - nbase)) * 32;
#pragma unroll
      for (int it = 0; it < 8; ++it) {
        int s = tid + it * 256;
        if (s < nn) {
          int gid = rows1[nbase + (s >> 5)];
          if (gid < 0) gid = 0;
          v[it] = it4[(size_t)gid * 32 + (s & 31)];
        }
      }
    } else {
#pragma unroll
      for (int it = 0; it < 7; ++it) {
        int s = tid + it * 256;
        if (s < SLEN * 32) {
          int gid = rowsS[s >> 5];
          if (gid < 0) gid = 0;
          v[it] = it4[(size_t)gid * 32 + (s & 31)];
        }
      }
    }

    // -- matvec: wave w computes j in [4w,4w+4) for item=lane --
    if (lane < cnt) {
      float a0 = 0.f, a1 = 0.f, a2 = 0.f, a3 = 0.f;
      const float4* er4 = reinterpret_cast<const float4*>(&ebuf[lane * ESTR]);
      const float* wc = &W1[(size_t)D * 16 + 4 * w];
#pragma unroll
      for (int t = 0; t < 32; ++t) {
        float4 e = er4[t];
        const float* wr = wc + (4 * t) * 16;  // wave-uniform -> s_load
        a0 = fmaf(e.x, wr[0], a0);  a1 = fmaf(e.x, wr[1], a1);
        a2 = fmaf(e.x, wr[2], a2);  a3 = fmaf(e.x, wr[3], a3);
        a0 = fmaf(e.y, wr[16], a0); a1 = fmaf(e.y, wr[17], a1);
        a2 = fmaf(e.y, wr[18], a2); a3 = fmaf(e.y, wr[19], a3);
        a0 = fmaf(e.z, wr[32], a0); a1 = fmaf(e.z, wr[33], a1);
        a2 = fmaf(e.z, wr[34], a2); a3 = fmaf(e.z, wr[35], a3);
        a0 = fmaf(e.w, wr[48], a0); a1 = fmaf(e.w, wr[49], a1);
        a2 = fmaf(e.w, wr[50], a2); a3 = fmaf(e.w, wr[51], a3);
      }
      float hs = fmaxf(upart_sh[4 * w + 0] + a0, 0.f) * w2a;
      hs = fmaf(fmaxf(upart_sh[4 * w + 1] + a1, 0.f), w2b, hs);
      hs = fmaf(fmaxf(upart_sh[4 * w + 2] + a2, 0.f), w2c, hs);
      hs = fmaf(fmaxf(upart_sh[4 * w + 3] + a3, 0.f), w2d, hs);
      hspart[w * 65 + lane] = hs;
    }
    __syncthreads();

    // -- finalize logits -> unnormalized weights (no max-shift: |lg| tiny) --
    if (tid < cnt) {
      float lg = hspart[tid] + hspart[65 + tid] + hspart[130 + tid] +
                 hspart[195 + tid] + b2v;
      float p = (rows1[base + tid] >= 0) ? expf(lg) : 0.f;
      w_sh[tid] = p;
      pacc += p;
    }
    __syncthreads();

    // -- weighted accumulate (float4 per thread, bank-balanced b128 reads) --
    for (int l = g; l < cnt; l += 8) {
      float pw = w_sh[l];
      float4 e = reinterpret_cast<const float4*>(&ebuf[l * ESTR])[q];
      uacc.x = fmaf(pw, e.x, uacc.x);
      uacc.y = fmaf(pw, e.y, uacc.y);
      uacc.z = fmaf(pw, e.z, uacc.z);
      uacc.w = fmaf(pw, e.w, uacc.w);
    }
    __syncthreads();
  }

  // ---- u_long -> ebuf row 0 ; stage-2 rows -> ebuf rows 1..50 ----
  float4* part4 = reinterpret_cast<float4*>(&ebuf[52 * ESTR]);  // rows 52..59 dead
  part4[tid] = uacc;
  const float invS1 = 1.f / block_sum(pacc, red_sh);  // barriers publish part4
  if (tid < 32) {
    float4 t = part4[tid];
#pragma unroll
    for (int gg = 1; gg < 8; ++gg) {
      float4 o = part4[gg * 32 + tid];
      t.x += o.x; t.y += o.y; t.z += o.z; t.w += o.w;
    }
    t.x *= invS1; t.y *= invS1; t.z *= invS1; t.w *= invS1;
    reinterpret_cast<float4*>(ebuf)[tid] = t;  // row 0 = u_long
  }
#pragma unroll
  for (int it = 0; it < 7; ++it) {
    int s = tid + it * 256;
    if (s < SLEN * 32)
      *reinterpret_cast<float4*>(&ebuf[((s >> 5) + 1) * ESTR + 4 * (s & 31)]) = v[it];
  }
  __syncthreads();

  // ================= stage 2: rows 0..50 = [u_long] + S =================
  const int n2 = 1 + SLEN;  // 51
  if (lane < n2) {
    float a0 = 0.f, a1 = 0.f, a2 = 0.f, a3 = 0.f;
    const float4* er4 = reinterpret_cast<const float4*>(&ebuf[lane * ESTR]);
    const float* wc = &W1[(size_t)D * 16 + 4 * w];
#pragma unroll
    for (int t = 0; t < 32; ++t) {
      float4 e = er4[t];
      const float* wr = wc + (4 * t) * 16;
      a0 = fmaf(e.x, wr[0], a0);  a1 = fmaf(e.x, wr[1], a1);
      a2 = fmaf(e.x, wr[2], a2);  a3 = fmaf(e.x, wr[3], a3);
      a0 = fmaf(e.y, wr[16], a0); a1 = fmaf(e.y, wr[17], a1);
      a2 = fmaf(e.y, wr[18], a2); a3 = fmaf(e.y, wr[19], a3);
      a0 = fmaf(e.z, wr[32], a0); a1 = fmaf(e.z, wr[33], a1);
      a2 = fmaf(e.z, wr[34], a2); a3 = fmaf(e.z, wr[35], a3);
      a0 = fmaf(e.w, wr[48], a0); a1 = fmaf(e.w, wr[49], a1);
      a2 = fmaf(e.w, wr[50], a2); a3 = fmaf(e.w, wr[51], a3);
    }
    float hs = fmaxf(upart_sh[4 * w + 0] + a0, 0.f) * w2a;
    hs = fmaf(fmaxf(upart_sh[4 * w + 1] + a1, 0.f), w2b, hs);
    hs = fmaf(fmaxf(upart_sh[4 * w + 2] + a2, 0.f), w2c, hs);
    hs = fmaf(fmaxf(upart_sh[4 * w + 3] + a3, 0.f), w2d, hs);
    hspart[w * 65 + lane] = hs;
  }
  __syncthreads();

  float p2 = 0.f;
  if (tid < n2) {
    float lg = hspart[tid] + hspart[65 + tid] + hspart[130 + tid] +
               hspart[195 + tid] + b2v;
    bool valid = (tid == 0) || (rowsS[tid - 1] >= 0);
    p2 = valid ? expf(lg) : 0.f;
    w_sh[tid] = p2;
  }
  const float invS2 = 1.f / block_sum(p2, red_sh);  // barriers publish w_sh

  float4 uacc2 = make_float4(0.f, 0.f, 0.f, 0.f);
  for (int l = g; l < n2; l += 8) {
    float pw = w_sh[l];
    float4 e = reinterpret_cast<const float4*>(&ebuf[l * ESTR])[q];
    uacc2.x = fmaf(pw, e.x, uacc2.x);
    uacc2.y = fmaf(pw, e.y, uacc2.y);
    uacc2.z = fmaf(pw, e.z, uacc2.z);
    uacc2.w = fmaf(pw, e.w, uacc2.w);
  }
  part4[tid] = uacc2;
  __syncthreads();

  // ---- score = dot(user_hybrid, item_emb) ----
  float sv = 0.f;
  if (tid < 32) {
    float4 t = part4[tid];
#pragma unroll
    for (int gg = 1; gg < 8; ++gg) {
      float4 o = part4[gg * 32 + tid];
      t.x += o.x; t.y += o.y; t.z += o.z; t.w += o.w;
    }
    float4 iv = it4[(size_t)item_inputs[b] * 32 + tid];
    sv = (t.x * iv.x + t.y * iv.y + t.z * iv.z + t.w * iv.w) * invS2;
  }
  float tot = block_sum(sv, red_sh);
  if (tid == 0) out[b] = tot;
}

extern "C" void kernel_launch(void* const* d_in, const int* in_sizes, int n_in,
                              void* d_out, int out_size, void* d_ws, size_t ws_size,
                              hipStream_t stream) {
  const float* user_table = (const float*)d_in[0];
  const float* item_table = (const float*)d_in[1];
  const float* W1 = (const float*)d_in[2];
  const float* b1 = (const float*)d_in[3];
  const float* W2 = (const float*)d_in[4];
  const float* b2 = (const float*)d_in[5];
  const int* user_inputs = (const int*)d_in[6];
  const int* L_inputs = (const int*)d_in[7];
  const int* S_inputs = (const int*)d_in[8];
  const int* item_inputs = (const int*)d_in[9];
  float* out = (float*)d_out;

  const int B = in_sizes[6];  // 4096
  din_kernel<<<B, 256, 0, stream>>>(user_table, item_table, W1, b1, W2, b2,
                                    user_inputs, L_inputs, S_inputs, item_inputs,
                                    out);
}

// Round 6
// 343.530 us; speedup vs baseline: 1.4291x; 1.4291x over previous
//
#include <hip/hip_runtime.h>
#include <math.h>

#define D 128
#define LLEN 200
#define SLEN 50
#define CH 64
#define ESTR 132          // floats; 528B row stride = 33*16 -> 16B-aligned rows, bank-balanced
#define NEG (-1e9f)

__device__ __forceinline__ float wave_red_sum(float v) {
#pragma unroll
  for (int m = 32; m >= 1; m >>= 1) v += __shfl_xor(v, m, 64);
  return v;
}
// 256-thread block sum; ALL threads must call.
__device__ __forceinline__ float block_sum(float v, float* red) {
  v = wave_red_sum(v);
  if ((threadIdx.x & 63) == 0) red[threadIdx.x >> 6] = v;
  __syncthreads();
  v = red[0] + red[1] + red[2] + red[3];
  __syncthreads();
  return v;
}

// gather one float4 slot: row rids[base + s/32] (clamped at 0), col s%32
__device__ __forceinline__ float4 gslot(const float4* it4, const int* rids,
                                        int base, int s) {
  int gid = rids[base + (s >> 5)];
  gid = gid < 0 ? 0 : gid;
  return it4[(size_t)gid * 32 + (s & 31)];
}

__global__ void __launch_bounds__(256, 4) din_kernel(
    const float* __restrict__ user_table, const float* __restrict__ item_table,
    const float* __restrict__ W1, const float* __restrict__ b1,
    const float* __restrict__ W2, const float* __restrict__ b2,
    const int* __restrict__ user_inputs, const int* __restrict__ L_inputs,
    const int* __restrict__ S_inputs, const int* __restrict__ item_inputs,
    float* __restrict__ out) {
  __shared__ __align__(16) float ebuf[CH * ESTR];  // staged rows + aliased scratch
  __shared__ float hspart[4 * 65];
  __shared__ float w_sh[CH];
  __shared__ int rows1[LLEN];
  __shared__ int rowsS[SLEN];
  __shared__ float upart_sh[16];
  __shared__ float red_sh[4];

  const int b = blockIdx.x;
  const int tid = threadIdx.x;
  const int lane = tid & 63;
  const int w = __builtin_amdgcn_readfirstlane(tid >> 6);  // wave id (W1 s_load)
  const int q = tid & 31, g = tid >> 5;                    // float4-accumulate roles
  const float4* it4 = reinterpret_cast<const float4*>(item_table);

  // ---- prolog: indices + user embedding (aliased into ebuf) ----
  float* u_sh = &ebuf[0];
  float* part = &ebuf[128];
  if (tid < D) u_sh[tid] = user_table[(size_t)user_inputs[b] * D + tid];
  if (tid < LLEN) rows1[tid] = L_inputs[(size_t)b * LLEN + tid];
  if (tid < SLEN) rowsS[tid] = S_inputs[(size_t)b * SLEN + tid];
  __syncthreads();

  // ---- chunk-0 prefetch into NAMED registers (no array -> no spill) ----
  float4 p0, p1, p2, p3, p4, p5, p6, p7;
  p0 = gslot(it4, rows1, 0, tid);
  p1 = gslot(it4, rows1, 0, tid + 256);
  p2 = gslot(it4, rows1, 0, tid + 512);
  p3 = gslot(it4, rows1, 0, tid + 768);
  p4 = gslot(it4, rows1, 0, tid + 1024);
  p5 = gslot(it4, rows1, 0, tid + 1280);
  p6 = gslot(it4, rows1, 0, tid + 1536);
  p7 = gslot(it4, rows1, 0, tid + 1792);

  // ---- u_part[j] = b1[j] + u @ W1[0:128,:] (overlaps prefetch latency) ----
  {
    int j = tid & 15, gg = tid >> 4;
    float p = 0.f;
#pragma unroll
    for (int t = 0; t < 8; ++t) {
      int d = gg * 8 + t;
      p = fmaf(u_sh[d], W1[d * 16 + j], p);
    }
    part[tid] = p;
  }
  __syncthreads();
  if (tid < 16) {
    float s = b1[tid];
#pragma unroll
    for (int gg = 0; gg < 16; ++gg) s += part[gg * 16 + tid];
    upart_sh[tid] = s;
  }
  __syncthreads();

  const float b2v = b2[0];
  const float w2a = W2[4 * w + 0], w2b = W2[4 * w + 1];
  const float w2c = W2[4 * w + 2], w2d = W2[4 * w + 3];

  float pacc = 0.f;
  float4 uacc = make_float4(0.f, 0.f, 0.f, 0.f);

#define EST(s) (((s) >> 5) * ESTR + 4 * ((s) & 31))

  // ================= stage 1: 4 chunks {64,64,64,8} =================
  for (int c = 0; c < 4; ++c) {
    const int base = c * CH;
    const int cnt = (base + CH <= LLEN) ? CH : (LLEN - base);

    // -- write prefetched rows to LDS (aligned ds_write_b128) --
    *reinterpret_cast<float4*>(&ebuf[EST(tid)]) = p0;
    if (cnt == CH) {
      *reinterpret_cast<float4*>(&ebuf[EST(tid + 256)]) = p1;
      *reinterpret_cast<float4*>(&ebuf[EST(tid + 512)]) = p2;
      *reinterpret_cast<float4*>(&ebuf[EST(tid + 768)]) = p3;
      *reinterpret_cast<float4*>(&ebuf[EST(tid + 1024)]) = p4;
      *reinterpret_cast<float4*>(&ebuf[EST(tid + 1280)]) = p5;
      *reinterpret_cast<float4*>(&ebuf[EST(tid + 1536)]) = p6;
      *reinterpret_cast<float4*>(&ebuf[EST(tid + 1792)]) = p7;
    }
    __syncthreads();

    // -- issue next prefetch: chunk c+1, or stage-2 rows on last chunk --
    if (c < 2) {  // next chunk is full 64 rows
      const int nb = (c + 1) * CH;
      p0 = gslot(it4, rows1, nb, tid);
      p1 = gslot(it4, rows1, nb, tid + 256);
      p2 = gslot(it4, rows1, nb, tid + 512);
      p3 = gslot(it4, rows1, nb, tid + 768);
      p4 = gslot(it4, rows1, nb, tid + 1024);
      p5 = gslot(it4, rows1, nb, tid + 1280);
      p6 = gslot(it4, rows1, nb, tid + 1536);
      p7 = gslot(it4, rows1, nb, tid + 1792);
    } else if (c == 2) {  // next chunk = 8 rows (256 slots)
      p0 = gslot(it4, rows1, 3 * CH, tid);
    } else {  // stage-2 S rows: 1600 slots (p6 tail clamped)
      p0 = gslot(it4, rowsS, 0, tid);
      p1 = gslot(it4, rowsS, 0, tid + 256);
      p2 = gslot(it4, rowsS, 0, tid + 512);
      p3 = gslot(it4, rowsS, 0, tid + 768);
      p4 = gslot(it4, rowsS, 0, tid + 1024);
      p5 = gslot(it4, rowsS, 0, tid + 1280);
      int s6 = tid + 1536; s6 = s6 < 1599 ? s6 : 1599;
      p6 = gslot(it4, rowsS, 0, s6);
    }

    // -- matvec: wave w computes j in [4w,4w+4) for item=lane --
    if (lane < cnt) {
      float a0 = 0.f, a1 = 0.f, a2 = 0.f, a3 = 0.f;
      const float4* er4 = reinterpret_cast<const float4*>(&ebuf[lane * ESTR]);
      const float* wc = &W1[(size_t)D * 16 + 4 * w];
#pragma unroll
      for (int t = 0; t < 32; ++t) {
        float4 e = er4[t];
        const float* wr = wc + (4 * t) * 16;  // wave-uniform -> s_load
        a0 = fmaf(e.x, wr[0], a0);  a1 = fmaf(e.x, wr[1], a1);
        a2 = fmaf(e.x, wr[2], a2);  a3 = fmaf(e.x, wr[3], a3);
        a0 = fmaf(e.y, wr[16], a0); a1 = fmaf(e.y, wr[17], a1);
        a2 = fmaf(e.y, wr[18], a2); a3 = fmaf(e.y, wr[19], a3);
        a0 = fmaf(e.z, wr[32], a0); a1 = fmaf(e.z, wr[33], a1);
        a2 = fmaf(e.z, wr[34], a2); a3 = fmaf(e.z, wr[35], a3);
        a0 = fmaf(e.w, wr[48], a0); a1 = fmaf(e.w, wr[49], a1);
        a2 = fmaf(e.w, wr[50], a2); a3 = fmaf(e.w, wr[51], a3);
      }
      float hs = fmaxf(upart_sh[4 * w + 0] + a0, 0.f) * w2a;
      hs = fmaf(fmaxf(upart_sh[4 * w + 1] + a1, 0.f), w2b, hs);
      hs = fmaf(fmaxf(upart_sh[4 * w + 2] + a2, 0.f), w2c, hs);
      hs = fmaf(fmaxf(upart_sh[4 * w + 3] + a3, 0.f), w2d, hs);
      hspart[w * 65 + lane] = hs;
    }
    __syncthreads();

    // -- finalize logits -> unnormalized weights (no max-shift: |lg| tiny) --
    if (tid < cnt) {
      float lg = hspart[tid] + hspart[65 + tid] + hspart[130 + tid] +
                 hspart[195 + tid] + b2v;
      float p = (rows1[base + tid] >= 0) ? expf(lg) : 0.f;
      w_sh[tid] = p;
      pacc += p;
    }
    __syncthreads();

    // -- weighted accumulate (float4 per thread, bank-balanced b128 reads) --
    for (int l = g; l < cnt; l += 8) {
      float pw = w_sh[l];
      float4 e = reinterpret_cast<const float4*>(&ebuf[l * ESTR])[q];
      uacc.x = fmaf(pw, e.x, uacc.x);
      uacc.y = fmaf(pw, e.y, uacc.y);
      uacc.z = fmaf(pw, e.z, uacc.z);
      uacc.w = fmaf(pw, e.w, uacc.w);
    }
    __syncthreads();
  }

  // ---- u_long -> ebuf row 0 ; stage-2 rows -> ebuf rows 1..50 ----
  float4* part4 = reinterpret_cast<float4*>(&ebuf[52 * ESTR]);  // rows 52..59 dead
  part4[tid] = uacc;
  const float invS1 = 1.f / block_sum(pacc, red_sh);  // barriers publish part4
  if (tid < 32) {
    float4 t = part4[tid];
#pragma unroll
    for (int gg = 1; gg < 8; ++gg) {
      float4 o = part4[gg * 32 + tid];
      t.x += o.x; t.y += o.y; t.z += o.z; t.w += o.w;
    }
    t.x *= invS1; t.y *= invS1; t.z *= invS1; t.w *= invS1;
    reinterpret_cast<float4*>(ebuf)[tid] = t;  // row 0 = u_long
  }
  // stage-2 staged rows shifted by +1 row (row 0 = u_long)
  *reinterpret_cast<float4*>(&ebuf[EST(tid) + ESTR]) = p0;
  *reinterpret_cast<float4*>(&ebuf[EST(tid + 256) + ESTR]) = p1;
  *reinterpret_cast<float4*>(&ebuf[EST(tid + 512) + ESTR]) = p2;
  *reinterpret_cast<float4*>(&ebuf[EST(tid + 768) + ESTR]) = p3;
  *reinterpret_cast<float4*>(&ebuf[EST(tid + 1024) + ESTR]) = p4;
  *reinterpret_cast<float4*>(&ebuf[EST(tid + 1280) + ESTR]) = p5;
  if (tid + 1536 < 1600)
    *reinterpret_cast<float4*>(&ebuf[EST(tid + 1536) + ESTR]) = p6;
  __syncthreads();

  // ================= stage 2: rows 0..50 = [u_long] + S =================
  const int n2 = 1 + SLEN;  // 51
  if (lane < n2) {
    float a0 = 0.f, a1 = 0.f, a2 = 0.f, a3 = 0.f;
    const float4* er4 = reinterpret_cast<const float4*>(&ebuf[lane * ESTR]);
    const float* wc = &W1[(size_t)D * 16 + 4 * w];
#pragma unroll
    for (int t = 0; t < 32; ++t) {
      float4 e = er4[t];
      const float* wr = wc + (4 * t) * 16;
      a0 = fmaf(e.x, wr[0], a0);  a1 = fmaf(e.x, wr[1], a1);
      a2 = fmaf(e.x, wr[2], a2);  a3 = fmaf(e.x, wr[3], a3);
      a0 = fmaf(e.y, wr[16], a0); a1 = fmaf(e.y, wr[17], a1);
      a2 = fmaf(e.y, wr[18], a2); a3 = fmaf(e.y, wr[19], a3);
      a0 = fmaf(e.z, wr[32], a0); a1 = fmaf(e.z, wr[33], a1);
      a2 = fmaf(e.z, wr[34], a2); a3 = fmaf(e.z, wr[35], a3);
      a0 = fmaf(e.w, wr[48], a0); a1 = fmaf(e.w, wr[49], a1);
      a2 = fmaf(e.w, wr[50], a2); a3 = fmaf(e.w, wr[51], a3);
    }
    float hs = fmaxf(upart_sh[4 * w + 0] + a0, 0.f) * w2a;
    hs = fmaf(fmaxf(upart_sh[4 * w + 1] + a1, 0.f), w2b, hs);
    hs = fmaf(fmaxf(upart_sh[4 * w + 2] + a2, 0.f), w2c, hs);
    hs = fmaf(fmaxf(upart_sh[4 * w + 3] + a3, 0.f), w2d, hs);
    hspart[w * 65 + lane] = hs;
  }
  __syncthreads();

  float pw2 = 0.f;
  if (tid < n2) {
    float lg = hspart[tid] + hspart[65 + tid] + hspart[130 + tid] +
               hspart[195 + tid] + b2v;
    bool valid = (tid == 0) || (rowsS[tid - 1] >= 0);
    pw2 = valid ? expf(lg) : 0.f;
    w_sh[tid] = pw2;
  }
  const float invS2 = 1.f / block_sum(pw2, red_sh);  // barriers publish w_sh

  float4 uacc2 = make_float4(0.f, 0.f, 0.f, 0.f);
  for (int l = g; l < n2; l += 8) {
    float pw = w_sh[l];
    float4 e = reinterpret_cast<const float4*>(&ebuf[l * ESTR])[q];
    uacc2.x = fmaf(pw, e.x, uacc2.x);
    uacc2.y = fmaf(pw, e.y, uacc2.y);
    uacc2.z = fmaf(pw, e.z, uacc2.z);
    uacc2.w = fmaf(pw, e.w, uacc2.w);
  }
  part4[tid] = uacc2;
  __syncthreads();

  // ---- score = dot(user_hybrid, item_emb) ----
  float sv = 0.f;
  if (tid < 32) {
    float4 t = part4[tid];
#pragma unroll
    for (int gg = 1; gg < 8; ++gg) {
      float4 o = part4[gg * 32 + tid];
      t.x += o.x; t.y += o.y; t.z += o.z; t.w += o.w;
    }
    float4 iv = it4[(size_t)item_inputs[b] * 32 + tid];
    sv = (t.x * iv.x + t.y * iv.y + t.z * iv.z + t.w * iv.w) * invS2;
  }
  float tot = block_sum(sv, red_sh);
  if (tid == 0) out[b] = tot;
}

extern "C" void kernel_launch(void* const* d_in, const int* in_sizes, int n_in,
                              void* d_out, int out_size, void* d_ws, size_t ws_size,
                              hipStream_t stream) {
  const float* user_table = (const float*)d_in[0];
  const float* item_table = (const float*)d_in[1];
  const float* W1 = (const float*)d_in[2];
  const float* b1 = (const float*)d_in[3];
  const float* W2 = (const float*)d_in[4];
  const float* b2 = (const float*)d_in[5];
  const int* user_inputs = (const int*)d_in[6];
  const int* L_inputs = (const int*)d_in[7];
  const int* S_inputs = (const int*)d_in[8];
  const int* item_inputs = (const int*)d_in[9];
  float* out = (float*)d_out;

  const int B = in_sizes[6];  // 4096
  din_kernel<<<B, 256, 0, stream>>>(user_table, item_table, W1, b1, W2, b2,
                                    user_inputs, L_inputs, S_inputs, item_inputs,
                                    out);
}